// Round 1
// baseline (92.823 us; speedup 1.0000x reference)
//
#include <hip/hip_runtime.h>

// Problem constants (SAN subtraction2): K=7, S=1, P=3, D=1, reflect pad.
// N=8, C=64, H=W=56 -> out_h=out_w=56, L=3136, KK=49.
// out[n,c,kk, oh*56+ow] = in2[n,c, refl(oh+i-3), refl(ow+j-3)] - in1[n,c,oh,ow]
// with kk = i*7+j.

#define KSZ 7
#define KK 49
#define HH 56
#define WW 56
// per-(n,c,kk) output row length in float4 units: 3136/4 = 784
#define L4 784
#define W4 14  // 56/4

__device__ __forceinline__ int refl56(int s) {
    // jnp.pad mode='reflect': [..,c,b,a | a..z | z,y,x,..] without edge repeat
    s = s < 0 ? -s : s;
    return s >= 56 ? 110 - s : s;
}

__global__ __launch_bounds__(256) void sub2_kernel(
    const float* __restrict__ in1,
    const float* __restrict__ in2,
    float* __restrict__ out,
    int total4)
{
    int idx = blockIdx.x * blockDim.x + threadIdx.x;
    if (idx >= total4) return;

    // idx = ((nc*KK + kk) * L4 + t), t in [0,784)
    int t    = idx % L4;
    int rest = idx / L4;
    int kk   = rest % KK;
    int nc   = rest / KK;

    int i = kk / KSZ;
    int j = kk % KSZ;

    int oh = t / W4;
    int ow = (t % W4) * 4;

    // input1: contiguous, 16B-aligned float4
    const float4 q = *reinterpret_cast<const float4*>(
        in1 + (nc * HH + oh) * WW + ow);

    // input2: row fixed by reflected vertical index, per-column reflect
    int rh = refl56(oh + i - 3);
    const float* p2 = in2 + (nc * HH + rh) * WW;
    int cb = ow + j - 3;

    float4 r;
    r.x = p2[refl56(cb + 0)] - q.x;
    r.y = p2[refl56(cb + 1)] - q.y;
    r.z = p2[refl56(cb + 2)] - q.z;
    r.w = p2[refl56(cb + 3)] - q.w;

    // out flat offset = ((nc*KK + kk)*3136 + oh*56 + ow) = idx*4 (aligned)
    *reinterpret_cast<float4*>(out + (size_t)idx * 4) = r;
}

extern "C" void kernel_launch(void* const* d_in, const int* in_sizes, int n_in,
                              void* d_out, int out_size, void* d_ws, size_t ws_size,
                              hipStream_t stream) {
    const float* in1 = (const float*)d_in[0];
    const float* in2 = (const float*)d_in[1];
    float* out = (float*)d_out;

    // total output elements = 8*64*49*3136 = 78,675,968 ; /4 = 19,668,992
    int total4 = out_size / 4;
    int block = 256;
    int grid = (total4 + block - 1) / block;
    sub2_kernel<<<grid, block, 0, stream>>>(in1, in2, out, total4);
}

// Round 2
// 62.941 us; speedup vs baseline: 1.4748x; 1.4748x over previous
//
#include <hip/hip_runtime.h>

// SAN subtraction2: K=7, S=1, P=3, D=1, reflect pad.
// N=8, C=64, H=W=56 -> out [8,64,49,3136] fp32.
// out[nc, kk=i*7+j, oh*56+ow] = in2[nc, refl(oh+i-3), refl(ow+j-3)] - in1[nc,oh,ow]
//
// Thread = (nc, i, oh, ow4): computes 7 j-outputs (7 float4 stores).
// - index math + row reflect amortized 7x
// - in2 column window [ow-3, ow+6] (10 floats) loaded once, reused across j
// - 7 independent nontemporal stores per thread (write-once 315MB stream)

typedef float f4 __attribute__((ext_vector_type(4)));

#define KSZ 7
#define KK 49
#define HH 56
#define WW 56
#define L 3136   // 56*56
#define W4 14    // 56/4

__device__ __forceinline__ int refl56(int s) {
    // jnp reflect (no edge repeat): s<0 -> -s ; s>=56 -> 110-s
    s = s < 0 ? -s : s;
    return s >= 56 ? 110 - s : s;
}

__global__ __launch_bounds__(256) void sub2_kernel(
    const float* __restrict__ in1,
    const float* __restrict__ in2,
    float* __restrict__ out,
    int total)
{
    int tid = blockIdx.x * blockDim.x + threadIdx.x;
    if (tid >= total) return;

    // tid = (nc*7 + i)*784 + t,  t = oh*14 + ow4
    int t    = tid % 784;
    int rest = tid / 784;
    int i    = rest % KSZ;
    int nc   = rest / KSZ;

    int oh = t / W4;
    int ow = (t % W4) * 4;

    // query: one aligned float4 (read 7x total across i, hits L1/L2)
    const f4 q = *reinterpret_cast<const f4*>(in1 + (nc * HH + oh) * WW + ow);

    // key row for this i (vertical reflect picks a real row)
    int rh = refl56(oh + i - 3);
    const float* __restrict__ row = in2 + (nc * HH + rh) * WW;

    // 10-wide column window, horizontal reflect per column (branchless)
    float v[10];
#pragma unroll
    for (int d = 0; d < 10; ++d)
        v[d] = row[refl56(ow + d - 3)];

    // out base for kk = i*7 + 0
    float* outp = out + ((size_t)(nc * KK + i * KSZ) * L + oh * WW + ow);
#pragma unroll
    for (int j = 0; j < KSZ; ++j) {
        f4 r;
        r.x = v[j + 0] - q.x;
        r.y = v[j + 1] - q.y;
        r.z = v[j + 2] - q.z;
        r.w = v[j + 3] - q.w;
        __builtin_nontemporal_store(r, reinterpret_cast<f4*>(outp));
        outp += L;
    }
}

extern "C" void kernel_launch(void* const* d_in, const int* in_sizes, int n_in,
                              void* d_out, int out_size, void* d_ws, size_t ws_size,
                              hipStream_t stream) {
    const float* in1 = (const float*)d_in[0];
    const float* in2 = (const float*)d_in[1];
    float* out = (float*)d_out;

    // threads = 512 nc * 7 i * 784 (oh,ow4) = 2,809,856
    int total = 512 * KSZ * 784;
    int block = 256;
    int grid = (total + block - 1) / block;
    sub2_kernel<<<grid, block, 0, stream>>>(in1, in2, out, total);
}